// Round 6
// baseline (296.653 us; speedup 1.0000x reference)
//
#include <hip/hip_runtime.h>
#include <hip/hip_bf16.h>

// Fused single-head attention, bf16 MFMA, barrier-free K-loops.
//   x[4,4096,1024] fp32, W_qkv[1024,192], b_qkv[192], W_out[64,1024], b_out[1024]
//   out[4,4096,1024] fp32
// All MFMA B-fragments load 16B-contiguous DIRECTLY from global (no LDS staging,
// no __syncthreads in any K-loop). A-fragments via wave-private LDS strips.
// prep -> qkv (Q pre-scaled 1/8, V transposed) -> attn partials (8 key-splits,
// no-max softmax) -> combine + out-proj.

#define LD 72  // LDS row stride (bf16 elems): 144 B, 16B-aligned, 4-bank rotate/row

typedef __attribute__((ext_vector_type(8))) short short8;   // 8 bf16 (MFMA A/B frag)
typedef __attribute__((ext_vector_type(4))) float floatx4;  // MFMA C/D frag

#define MFMA(a, b, c) __builtin_amdgcn_mfma_f32_16x16x32_bf16((a), (b), (c), 0, 0, 0)

__device__ __forceinline__ unsigned short f2bf(float f) {
  union { float f; unsigned u; } c; c.f = f;
  unsigned u = c.u + 0x7fffu + ((c.u >> 16) & 1u);  // RNE
  return (unsigned short)(u >> 16);
}
__device__ __forceinline__ float asf(unsigned u) {
  union { unsigned u; float f; } c; c.u = u; return c.f;
}

// ---------------- prep: WtQkv[n=192][k=1024] = W_qkv[k][n]; WtOut[e=1024][d=64] = W_out[d][e]
__global__ __launch_bounds__(256) void prep_kernel(
    const float* __restrict__ Wqkv, const float* __restrict__ Wout,
    unsigned short* __restrict__ WtQkv, unsigned short* __restrict__ WtOut) {
  int idx = blockIdx.x * 256 + threadIdx.x;
  if (idx < 192 * 1024) {
    int n = idx >> 10, k = idx & 1023;
    WtQkv[idx] = f2bf(Wqkv[k * 192 + n]);
  } else if (idx < 192 * 1024 + 1024 * 64) {
    int j = idx - 192 * 1024;
    int e = j >> 6, d = j & 63;
    WtOut[j] = f2bf(Wout[d * 1024 + e]);
  }
}

// ---------------- QKV: 16 rows/block, 1024 blocks. No LDS in K-loop: x a-frags
// converted fp32->bf16 in regs; W b-frags direct 16B global loads. Zero barriers
// until the V-transpose epilogue.
__global__ __launch_bounds__(256, 4) void qkv_kernel(
    const float* __restrict__ x, const unsigned short* __restrict__ WtQkv,
    const float* __restrict__ bqkv,
    unsigned short* __restrict__ Qg, unsigned short* __restrict__ Kg,
    unsigned short* __restrict__ Vtg) {
  __shared__ __align__(16) unsigned short vt[64 * 24];

  const int tid = threadIdx.x;
  const int wave = tid >> 6, lane = tid & 63, quad = lane >> 4, l16 = lane & 15;
  const int row0 = blockIdx.x * 16;

  floatx4 acc[3];
#pragma unroll
  for (int t = 0; t < 3; t++) acc[t] = (floatx4)(0.0f);

  const float* xrow = x + (size_t)(row0 + l16) * 1024 + quad * 8;

  for (int kc = 0; kc < 16; kc++) {
    // A-frags: x[16 rows][64 k] slice, each lane 2x(8 consecutive floats) -> bf16
    const float* xp = xrow + kc * 64;
    float4 x0 = *(const float4*)(xp);
    float4 x1 = *(const float4*)(xp + 4);
    float4 x2 = *(const float4*)(xp + 32);
    float4 x3 = *(const float4*)(xp + 36);
    short8 a0, a1;
    a0[0] = (short)f2bf(x0.x); a0[1] = (short)f2bf(x0.y);
    a0[2] = (short)f2bf(x0.z); a0[3] = (short)f2bf(x0.w);
    a0[4] = (short)f2bf(x1.x); a0[5] = (short)f2bf(x1.y);
    a0[6] = (short)f2bf(x1.z); a0[7] = (short)f2bf(x1.w);
    a1[0] = (short)f2bf(x2.x); a1[1] = (short)f2bf(x2.y);
    a1[2] = (short)f2bf(x2.z); a1[3] = (short)f2bf(x2.w);
    a1[4] = (short)f2bf(x3.x); a1[5] = (short)f2bf(x3.y);
    a1[6] = (short)f2bf(x3.z); a1[7] = (short)f2bf(x3.w);

    // B-frags: W rows (this wave's 48 output cols), 16B contiguous global
    const unsigned short* Wp = WtQkv + kc * 64 + quad * 8;
#pragma unroll
    for (int t = 0; t < 3; t++) {
      size_t n = (size_t)((wave * 3 + t) * 16 + l16) * 1024;
      short8 b0 = *(const short8*)(Wp + n);
      short8 b1 = *(const short8*)(Wp + n + 32);
      acc[t] = MFMA(a0, b0, acc[t]);
      acc[t] = MFMA(a1, b1, acc[t]);
    }
  }

  const int b = row0 >> 12, srow = row0 & 4095;
#pragma unroll
  for (int t = 0; t < 3; t++) {
    int tt = wave * 3 + t;
    int c = tt * 16 + l16;
    float bias = bqkv[c];
    int sec = tt >> 2, d = c & 63;
#pragma unroll
    for (int r = 0; r < 4; r++) {
      int lrow = quad * 4 + r;  // C layout: row=quad*4+r, col=tt*16+l16
      float v = acc[t][r] + bias;
      if (sec == 0)      Qg[(size_t)(row0 + lrow) * 64 + d] = f2bf(v * 0.125f);
      else if (sec == 1) Kg[(size_t)(row0 + lrow) * 64 + d] = f2bf(v);
      else               vt[d * 24 + lrow] = f2bf(v);  // LDS transpose for V
    }
  }
  __syncthreads();
  {  // Vt write: 16 elems (32 B) per d-row
    int d = tid >> 2, seg = tid & 3;
    uint2 vv = *(const uint2*)(&vt[d * 24 + seg * 4]);
    *(uint2*)(Vtg + ((size_t)b * 64 + d) * 4096 + srow + seg * 4) = vv;
  }
}

// ---------------- attention partial: block = 128 queries x 512-key split; barrier-free.
// Wave handles a 32-query strip (2 MFMA halves). K/V b-frags direct from global;
// Q and P via wave-private LDS strip. No-max softmax (Q pre-scaled), unnormalized O + l.
__global__ __launch_bounds__(256, 4) void attn_kernel(
    const unsigned short* __restrict__ Qg, const unsigned short* __restrict__ Kg,
    const unsigned short* __restrict__ Vtg,
    unsigned short* __restrict__ Opart, float* __restrict__ Lpart) {
  __shared__ __align__(16) unsigned short Qs[128 * LD];  // Q stage; then per-wave P strips

  const int tid = threadIdx.x;
  const int wave = tid >> 6, lane = tid & 63, quad = lane >> 4, l16 = lane & 15;
  const int bid = blockIdx.x;
  const int qt = bid & 31, split = (bid >> 5) & 7, b = bid >> 8;
  const int q0 = qt * 128, key0 = split * 512;

  {  // Q stage: 2 threads/row, 32 elems (64 B) each -- wave-local rows, no barrier
    int r = tid >> 1, seg = tid & 1;
    const uint4* s = (const uint4*)(Qg + ((size_t)b * 4096 + q0 + r) * 64 + seg * 32);
    uint4 w0 = s[0], w1 = s[1], w2 = s[2], w3 = s[3];
    *(uint4*)(&Qs[r * LD + seg * 32])      = w0;
    *(uint4*)(&Qs[r * LD + seg * 32 + 8])  = w1;
    *(uint4*)(&Qs[r * LD + seg * 32 + 16]) = w2;
    *(uint4*)(&Qs[r * LD + seg * 32 + 24]) = w3;
  }
  short8 aq[2][2];
#pragma unroll
  for (int h = 0; h < 2; h++) {
    aq[h][0] = *(const short8*)(&Qs[(wave * 32 + h * 16 + l16) * LD + quad * 8]);
    aq[h][1] = *(const short8*)(&Qs[(wave * 32 + h * 16 + l16) * LD + 32 + quad * 8]);
  }
  unsigned short* Pw = &Qs[wave * 32 * LD];  // reuse this wave's own rows as P strip

  floatx4 o[2][4];
  float lsum[2][4];
#pragma unroll
  for (int h = 0; h < 2; h++)
#pragma unroll
    for (int t = 0; t < 4; t++) { o[h][t] = (floatx4)(0.0f); lsum[h][t] = 0.0f; }

  const unsigned short* Kbase = Kg + ((size_t)b * 4096 + key0) * 64 + quad * 8;
  const unsigned short* Vbase = Vtg + ((size_t)b * 64 + l16) * 4096 + key0 + quad * 8;

#pragma unroll 1
  for (int kc = 0; kc < 8; kc++) {
    // K b-frags: 16B contiguous, wave covers 16 full 128B rows per frag pair
    const unsigned short* Kp = Kbase + (size_t)(kc * 64 + l16) * 64;
    short8 kb0[4], kb1[4];
#pragma unroll
    for (int t = 0; t < 4; t++) {
      kb0[t] = *(const short8*)(Kp + (size_t)t * 1024);
      kb1[t] = *(const short8*)(Kp + (size_t)t * 1024 + 32);
    }
    // S = Q K^T for both 16-q halves; exp + P store (wave-private strip)
#pragma unroll
    for (int h = 0; h < 2; h++) {
      floatx4 sc[4];
#pragma unroll
      for (int t = 0; t < 4; t++) {
        sc[t] = MFMA(aq[h][0], kb0[t], (floatx4)(0.0f));
        sc[t] = MFMA(aq[h][1], kb1[t], sc[t]);
      }
#pragma unroll
      for (int r = 0; r < 4; r++) {
#pragma unroll
        for (int t = 0; t < 4; t++) {
          float pv = __expf(sc[t][r]);
          lsum[h][r] += pv;
          Pw[(h * 16 + quad * 4 + r) * LD + t * 16 + l16] = f2bf(pv);
        }
      }
    }
    // V b-frags (Vt[d][s]: 16B contiguous) then P a-frags, PV accumulate
    const unsigned short* Vp = Vbase + kc * 64;
    short8 vb0[4], vb1[4];
#pragma unroll
    for (int t = 0; t < 4; t++) {
      vb0[t] = *(const short8*)(Vp + (size_t)t * 16 * 4096);
      vb1[t] = *(const short8*)(Vp + (size_t)t * 16 * 4096 + 32);
    }
#pragma unroll
    for (int h = 0; h < 2; h++) {
      short8 ap0 = *(const short8*)(&Pw[(h * 16 + l16) * LD + quad * 8]);
      short8 ap1 = *(const short8*)(&Pw[(h * 16 + l16) * LD + 32 + quad * 8]);
#pragma unroll
      for (int t = 0; t < 4; t++) {
        o[h][t] = MFMA(ap0, vb0[t], o[h][t]);
        o[h][t] = MFMA(ap1, vb1[t], o[h][t]);
      }
    }
  }

  // reduce l across the 16 key-cols held in l16
#pragma unroll
  for (int h = 0; h < 2; h++)
#pragma unroll
    for (int r = 0; r < 4; r++) {
      float s = lsum[h][r];
#pragma unroll
      for (int off = 1; off < 16; off <<= 1) s += __shfl_xor(s, off, 64);
      lsum[h][r] = s;
    }

  unsigned short* Ob = Opart + ((size_t)bid * 128 + wave * 32) * 64;
#pragma unroll
  for (int h = 0; h < 2; h++)
#pragma unroll
    for (int t = 0; t < 4; t++)
#pragma unroll
      for (int r = 0; r < 4; r++)
        Ob[(h * 16 + quad * 4 + r) * 64 + t * 16 + l16] = f2bf(o[h][t][r]);
  if (l16 == 0) {
#pragma unroll
    for (int h = 0; h < 2; h++)
#pragma unroll
      for (int r = 0; r < 4; r++)
        Lpart[bid * 128 + wave * 32 + h * 16 + quad * 4 + r] = lsum[h][r];
  }
}

// ---------------- combine 8 partials + fused out-proj; barrier-free.
// block = (batch, 128-q tile, 128-e chunk); W b-frags direct from global.
__global__ __launch_bounds__(256, 4) void combine_kernel(
    const unsigned short* __restrict__ Opart, const float* __restrict__ Lpart,
    const unsigned short* __restrict__ WtOut, const float* __restrict__ bout,
    float* __restrict__ out) {
  __shared__ __align__(16) unsigned short Cs[128 * LD];

  const int tid = threadIdx.x;
  const int wave = tid >> 6, lane = tid & 63, quad = lane >> 4, l16 = lane & 15;
  const int bid = blockIdx.x;
  const int eq = bid & 7, qt = (bid >> 3) & 31, b = bid >> 8;
  const int e0 = eq * 128;

  // sum 8 partials; thread owns (q = tid>>1, 32 d at dh) -- rows are wave-local
  const int q = tid >> 1, dh = (tid & 1) * 32;
  float accv[32];
#pragma unroll
  for (int i = 0; i < 32; i++) accv[i] = 0.0f;
  float lq = 0.0f;
#pragma unroll
  for (int s = 0; s < 8; s++) {
    int pid = qt + 32 * s + 256 * b;
    const uint4* sv = (const uint4*)(Opart + ((size_t)pid * 128 + q) * 64 + dh);
    unsigned uu[16];
    *(uint4*)(&uu[0])  = sv[0];
    *(uint4*)(&uu[4])  = sv[1];
    *(uint4*)(&uu[8])  = sv[2];
    *(uint4*)(&uu[12]) = sv[3];
#pragma unroll
    for (int i = 0; i < 16; i++) {
      accv[2 * i]     += asf(uu[i] << 16);
      accv[2 * i + 1] += asf(uu[i] & 0xFFFF0000u);
    }
    lq += Lpart[pid * 128 + q];
  }
  float inv = 1.0f / lq;
#pragma unroll
  for (int g = 0; g < 4; g++) {
    short8 cpk;
#pragma unroll
    for (int i = 0; i < 8; i++) cpk[i] = (short)f2bf(accv[g * 8 + i] * inv);
    *(short8*)(&Cs[q * LD + dh + g * 8]) = cpk;
  }
  // wave-local round-trip: rows [wave*32, wave*32+32) written by this wave only
  short8 ao[2][2];
#pragma unroll
  for (int h = 0; h < 2; h++) {
    ao[h][0] = *(const short8*)(&Cs[(wave * 32 + h * 16 + l16) * LD + quad * 8]);
    ao[h][1] = *(const short8*)(&Cs[(wave * 32 + h * 16 + l16) * LD + 32 + quad * 8]);
  }

  floatx4 a2[2][8];
#pragma unroll
  for (int h = 0; h < 2; h++)
#pragma unroll
    for (int t = 0; t < 8; t++) a2[h][t] = (floatx4)(0.0f);
#pragma unroll
  for (int t = 0; t < 8; t++) {
    const unsigned short* wp = WtOut + (size_t)(e0 + t * 16 + l16) * 64 + quad * 8;
    short8 wb0 = *(const short8*)(wp);
    short8 wb1 = *(const short8*)(wp + 32);
#pragma unroll
    for (int h = 0; h < 2; h++) {
      a2[h][t] = MFMA(ao[h][0], wb0, a2[h][t]);
      a2[h][t] = MFMA(ao[h][1], wb1, a2[h][t]);
    }
  }
  const size_t orow0 = (size_t)b * 4096 + qt * 128 + wave * 32;
#pragma unroll
  for (int h = 0; h < 2; h++)
#pragma unroll
    for (int t = 0; t < 8; t++) {
      int e = e0 + t * 16 + l16;
      float bo = bout[e];
#pragma unroll
      for (int r = 0; r < 4; r++)
        out[(orow0 + h * 16 + quad * 4 + r) * 1024 + e] = a2[h][t][r] + bo;
    }
}

extern "C" void kernel_launch(void* const* d_in, const int* in_sizes, int n_in,
                              void* d_out, int out_size, void* d_ws, size_t ws_size,
                              hipStream_t stream) {
  const float* x    = (const float*)d_in[0];  // [4,4096,1024]
  const float* Wqkv = (const float*)d_in[1];  // [1024,192]
  const float* bqkv = (const float*)d_in[2];  // [192]
  const float* Wout = (const float*)d_in[3];  // [64,1024]
  const float* bout = (const float*)d_in[4];  // [1024]
  float* out = (float*)d_out;                 // [4,4096,1024]

  unsigned short* ws = (unsigned short*)d_ws;
  unsigned short* Qg    = ws;                  // 16384*64 (pre-scaled by 1/8)
  unsigned short* Kg    = Qg + 1048576;        // 16384*64
  unsigned short* Vtg   = Kg + 1048576;        // [4][64][4096]
  unsigned short* WtQkv = Vtg + 1048576;       // [192][1024]
  unsigned short* WtOut = WtQkv + 196608;      // [1024][64]
  unsigned short* Opart = WtOut + 65536;       // [1024 pid][128 q][64 d] bf16
  float*          Lpart = (float*)(Opart + 8388608);  // [1024][128]

  prep_kernel<<<1024, 256, 0, stream>>>(Wqkv, Wout, WtQkv, WtOut);
  qkv_kernel<<<1024, 256, 0, stream>>>(x, WtQkv, bqkv, Qg, Kg, Vtg);
  attn_kernel<<<1024, 256, 0, stream>>>(Qg, Kg, Vtg, Opart, Lpart);
  combine_kernel<<<1024, 256, 0, stream>>>(Opart, Lpart, WtOut, bout, out);
}